// Round 16
// baseline (229.265 us; speedup 1.0000x reference)
//
#include <hip/hip_runtime.h>
#include <math.h>

// B=2, S=2048, D=1024, H=16, DK=64, NUM_BUCKETS=32, MAX_DIST=128, SM_SCALE=0.25
// Softmax in log2 domain: Wq pre-scaled by 0.25*log2(e), bias table pre-scaled by log2(e).
// attn (R12/R14-verified): 32x32x16 MFMA, swapped QK^T, in-register P redistribution,
// split-K pair-iteration. gemm_qkv: 256^2 8-phase schedule (T3+T4+T5). R15->R16 fix:
// __launch_bounds__(512, 2) — R15's default occupancy heuristic capped VGPR at 128 and
// spilled the 128-VGPR accumulator block to scratch (WRITE_SIZE 212MB, MfmaUtil 6%).

typedef _Float16 f16;
typedef _Float16 f16x4 __attribute__((ext_vector_type(4)));
typedef _Float16 f16x8 __attribute__((ext_vector_type(8)));
typedef float f32x4 __attribute__((ext_vector_type(4)));
typedef float f32x16 __attribute__((ext_vector_type(16)));
typedef unsigned int u32;
typedef u32 u32x4 __attribute__((ext_vector_type(4)));

#define MFMA16(a, b, c) __builtin_amdgcn_mfma_f32_16x16x32_f16((a), (b), (c), 0, 0, 0)
#define MFMA32(a, b, c) __builtin_amdgcn_mfma_f32_32x32x16_f16((a), (b), (c), 0, 0, 0)

static __device__ __forceinline__ float EXP2(float x) {
  float r;
  asm("v_exp_f32 %0, %1" : "=v"(r) : "v"(x));
  return r;
}

static __device__ __forceinline__ u32 pk2(float a, float b) {
  return __builtin_bit_cast(u32, __builtin_amdgcn_cvt_pkrtz(a, b));
}
static __device__ __forceinline__ void swap32(u32& a, u32& b) {
  asm volatile("v_permlane32_swap_b32 %0, %1" : "+v"(a), "+v"(b));
}

#define KEEPV8(v8)                                                        \
  do {                                                                    \
    u32x4 _t = __builtin_bit_cast(u32x4, (v8));                           \
    asm volatile("" ::"v"(_t[0]), "v"(_t[1]), "v"(_t[2]), "v"(_t[3]));    \
  } while (0)

// async global->LDS, 16B per lane; lds base must be wave-uniform (HW adds lane*16)
__device__ __forceinline__ void gload16(const f16* g, f16* l) {
  __builtin_amdgcn_global_load_lds(
      (const __attribute__((address_space(1))) void*)g,
      (__attribute__((address_space(3))) void*)l, 16, 0, 0);
}

// ---------------------------------------------------------------- prep kernel
__global__ void prep_kernel(const float* __restrict__ X, const float* __restrict__ w0,
                            const float* __restrict__ w1, const float* __restrict__ w2,
                            const float* __restrict__ w3, const float* __restrict__ relb,
                            f16x4* __restrict__ xh, f16* __restrict__ wt,
                            f16* __restrict__ bias_rel) {
  const int z = blockIdx.z;
  const int tx = threadIdx.x, ty = threadIdx.y;
  if (z < 4) {
    const float* w = (z == 0) ? w0 : (z == 1) ? w1 : (z == 2) ? w2 : w3;
    float sc = (z == 0) ? 0.36067376022224085f : 1.0f;  // 0.25 * log2(e)
    __shared__ float tile[32][33];
    int kt = blockIdx.x * 32, nt = blockIdx.y * 32;
#pragma unroll
    for (int i = 0; i < 4; ++i)
      tile[ty + i * 8][tx] = w[(size_t)(kt + ty + i * 8) * 1024 + nt + tx];
    __syncthreads();
#pragma unroll
    for (int i = 0; i < 4; ++i)
      wt[((size_t)z * 1024 + nt + ty + i * 8) * 1024 + kt + tx] =
          (f16)(tile[tx][ty + i * 8] * sc);
  } else if (z == 4) {
    if (blockIdx.x >= 8) return;
    int idx = (blockIdx.x * 32 + blockIdx.y) * 256 + ty * 32 + tx;  // 0..65535
    int h = idx >> 12;
    int r = idx & 4095;
    int rp = r - 2048;
    if (rp < -2047) rp = -2047;
    int bucket = (rp > 0) ? 16 : 0;
    int rpa = (rp < 0) ? -rp : rp;
    if (rpa < 8) {
      bucket += rpa;
    } else {
      int large = 8 + (int)(logf((float)rpa / 8.0f) / logf(16.0f) * 8.0f);
      bucket += (large < 15) ? large : 15;
    }
    bias_rel[idx] = (f16)(relb[bucket * 16 + h] * 1.4426950408889634f);
  } else {
    const float4* x4 = (const float4*)X;
    int i = (blockIdx.x * 32 + blockIdx.y) * 256 + ty * 32 + tx;
#pragma unroll
    for (int rep = 0; rep < 4; ++rep, i += 262144) {
      float4 v = x4[i];
      f16x4 o;
      o[0] = (f16)v.x; o[1] = (f16)v.y; o[2] = (f16)v.z; o[3] = (f16)v.w;
      xh[i] = o;
    }
  }
}

// ---------------------------------------------------------------- 256^2 8-phase GEMM
// C[M=4096][N=3072] = Xh[m][k] . Wt[n][k]^T, K=1024. 192 blocks x 512 thr (8 waves 2Mx4N).
// LDS: 2 slots x (A[256][64] + B[256][64]) f16 = 128 KiB, chunk-swizzle slot c^(row&7).
// Slot s computed in 4 quadrant-phases while the other slot is refilled 1 half-tile/phase.
// Counted vmcnt(2) at phases 0/4 (epilogue: vmcnt(0)); 2 raw s_barriers per phase.

#define FDECL f16x8 af[4][2]; f16x8 bf[2][2]
#define FRAGS(S, Q)                                                                 \
  {                                                                                 \
    const f16* bA_ = sAf + (S) * 16384;                                             \
    const f16* bB_ = sBf + (S) * 16384;                                             \
    const int mb_ = wr * 128 + ((Q) >> 1) * 64;                                     \
    const int nb_ = wc * 64 + ((Q) & 1) * 32;                                       \
    _Pragma("unroll") for (int mf = 0; mf < 4; ++mf) {                              \
      int r_ = mb_ + mf * 16 + cL;                                                  \
      _Pragma("unroll") for (int ks = 0; ks < 2; ++ks)                              \
          af[mf][ks] =                                                              \
          *(const f16x8*)&bA_[r_ * 64 + ((((ks << 2) | g) ^ (r_ & 7)) << 3)];       \
    }                                                                               \
    _Pragma("unroll") for (int nf = 0; nf < 2; ++nf) {                              \
      int r_ = nb_ + nf * 16 + cL;                                                  \
      _Pragma("unroll") for (int ks = 0; ks < 2; ++ks)                              \
          bf[nf][ks] =                                                              \
          *(const f16x8*)&bB_[r_ * 64 + ((((ks << 2) | g) ^ (r_ & 7)) << 3)];       \
    }                                                                               \
  }
#define MFMAQ(Q)                                                                    \
  {                                                                                 \
    __builtin_amdgcn_s_setprio(1);                                                  \
    _Pragma("unroll") for (int mf = 0; mf < 4; ++mf)                                \
        _Pragma("unroll") for (int nf = 0; nf < 2; ++nf)                            \
            _Pragma("unroll") for (int ks = 0; ks < 2; ++ks)                        \
                acc[((Q) >> 1) * 4 + mf][((Q) & 1) * 2 + nf] =                      \
        MFMA16(af[mf][ks], bf[nf][ks],                                              \
               acc[((Q) >> 1) * 4 + mf][((Q) & 1) * 2 + nf]);                       \
    __builtin_amdgcn_s_setprio(0);                                                  \
  }
#define BARX __builtin_amdgcn_s_barrier()
#define VW2 asm volatile("s_waitcnt vmcnt(2)" ::: "memory")
#define VW0 asm volatile("s_waitcnt vmcnt(0)" ::: "memory")
#define STG_A(S, kt, h)                                                             \
  {                                                                                 \
    gload16(gAp[2 * (h)] + (size_t)(kt) * 64,                                       \
            sAf + (S) * 16384 + w * 512 + (2 * (h)) * 4096);                        \
    gload16(gAp[2 * (h) + 1] + (size_t)(kt) * 64,                                   \
            sAf + (S) * 16384 + w * 512 + (2 * (h) + 1) * 4096);                    \
  }
#define STG_B(S, kt, h)                                                             \
  {                                                                                 \
    gload16(gBp[2 * (h)] + (size_t)(kt) * 64,                                       \
            sBf + (S) * 16384 + w * 512 + (2 * (h)) * 4096);                        \
    gload16(gBp[2 * (h) + 1] + (size_t)(kt) * 64,                                   \
            sBf + (S) * 16384 + w * 512 + (2 * (h) + 1) * 4096);                    \
  }

__global__ __launch_bounds__(512, 2) void gemm_qkv256_kernel(const f16* __restrict__ Xh,
                                                             const f16* __restrict__ Wt,
                                                             f16* __restrict__ Qh,
                                                             f16* __restrict__ Kh,
                                                             f16* __restrict__ Vt) {
  __shared__ __align__(16) f16 sA[2][16384];
  __shared__ __align__(16) f16 sB[2][16384];
  f16* sAf = &sA[0][0];
  f16* sBf = &sB[0][0];
  const int p = blockIdx.x;                 // 0..191, XCD-swizzled (192 % 8 == 0)
  const int L = (p & 7) * 24 + (p >> 3);
  const int bx = L % 12, by = L / 12;
  const int mrow0 = by * 256, ncol0 = bx * 256;
  const int t = threadIdx.x, lane = t & 63, w = t >> 6;
  const int wr = w >> 2, wc = w & 3;
  const int cL = lane & 15, g = lane >> 4;

  // staging pointers: thread stages chunks c0+512i (i=0..3); row=c>>3, pre-swizzled col
  const int c0 = w * 64 + lane;
  const f16* gAp[4];
  const f16* gBp[4];
#pragma unroll
  for (int i = 0; i < 4; ++i) {
    int c = c0 + 512 * i;
    int row = c >> 3;
    int col8 = ((c & 7) ^ (row & 7)) << 3;
    gAp[i] = Xh + (size_t)(mrow0 + row) * 1024 + col8;
    gBp[i] = Wt + (size_t)(ncol0 + row) * 1024 + col8;
  }

  f32x4 acc[8][4] = {};

  // prologue: fill slot 0 with K-tile 0 (8 loads/thread)
  STG_A(0, 0, 0); STG_A(0, 0, 1); STG_B(0, 0, 0); STG_B(0, 0, 1);

#pragma unroll 1
  for (int it = 0; it < 8; ++it) {
    const int kt1 = 2 * it + 1, kt2 = 2 * it + 2;
    // phases 0-3: compute slot 0 (tile 2it); refill slot 1 <- tile 2it+1
    { FDECL; STG_A(1, kt1, 0); VW2; BARX; FRAGS(0, 0); MFMAQ(0); BARX; }
    { FDECL; FRAGS(0, 1); STG_A(1, kt1, 1); BARX; MFMAQ(1); BARX; }
    { FDECL; FRAGS(0, 2); STG_B(1, kt1, 0); BARX; MFMAQ(2); BARX; }
    { FDECL; FRAGS(0, 3); STG_B(1, kt1, 1); BARX; MFMAQ(3); BARX; }
    // phases 4-7: compute slot 1 (tile 2it+1); refill slot 0 <- tile 2it+2
    if (it < 7) {
      { FDECL; STG_A(0, kt2, 0); VW2; BARX; FRAGS(1, 0); MFMAQ(0); BARX; }
      { FDECL; FRAGS(1, 1); STG_A(0, kt2, 1); BARX; MFMAQ(1); BARX; }
      { FDECL; FRAGS(1, 2); STG_B(0, kt2, 0); BARX; MFMAQ(2); BARX; }
      { FDECL; FRAGS(1, 3); STG_B(0, kt2, 1); BARX; MFMAQ(3); BARX; }
    } else {
      { FDECL; VW0; BARX; FRAGS(1, 0); MFMAQ(0); BARX; }
      { FDECL; FRAGS(1, 1); BARX; MFMAQ(1); BARX; }
      { FDECL; FRAGS(1, 2); BARX; MFMAQ(2); BARX; }
      { FDECL; FRAGS(1, 3); BARX; MFMAQ(3); BARX; }
    }
  }

  // epilogue: scatter Q,K [b][h][s][dk] / V^T [b][h][dk][s]
  const int which = (ncol0 + wc * 64) >> 10;
#pragma unroll
  for (int mf = 0; mf < 8; ++mf) {
#pragma unroll
    for (int nf = 0; nf < 4; ++nf) {
#pragma unroll
      for (int j = 0; j < 4; ++j) {
        int tt = mrow0 + wr * 128 + mf * 16 + g * 4 + j;
        int b = tt >> 11, s = tt & 2047;
        int col = (ncol0 + wc * 64 + nf * 16 + cL) & 1023;
        int hh = col >> 6, dk = col & 63;
        f16 val = (f16)acc[mf][nf][j];
        if (which == 0)
          Qh[(((size_t)b * 16 + hh) * 2048 + s) * 64 + dk] = val;
        else if (which == 1)
          Kh[(((size_t)b * 16 + hh) * 2048 + s) * 64 + dk] = val;
        else
          Vt[(((size_t)b * 16 + hh) * 64 + dk) * 2048 + s] = val;
      }
    }
  }
}

// ---------------------------------------------------------------- GEMM 128x128, BK=32
__device__ __forceinline__ void gemm128_core(const f16* __restrict__ A, const f16* __restrict__ Bt,
                                             int mrow, int ncol0, f16* sm /*[2][8192]*/,
                                             f32x4 acc[4][4]) {
  const int t = threadIdx.x;
  const int lane = t & 63, w = t >> 6;
  const int cL = lane & 15, g = lane >> 4;
  const int wr = w >> 1, wc = w & 1;

  const int c0 = w * 128 + lane;
  const int c1 = c0 + 64;
  const int rA0 = c0 >> 2, kA0 = ((c0 & 3) ^ (rA0 & 3)) << 3;
  const int rA1 = c1 >> 2, kA1 = ((c1 & 3) ^ (rA1 & 3)) << 3;
  const f16* gA0 = A + (size_t)(mrow + rA0) * 1024 + kA0;
  const f16* gA1 = A + (size_t)(mrow + rA1) * 1024 + kA1;
  const f16* gB0 = Bt + (size_t)(ncol0 + rA0) * 1024 + kA0;
  const f16* gB1 = Bt + (size_t)(ncol0 + rA1) * 1024 + kA1;
  const int lds0 = (w * 2) * 512, lds1 = (w * 2 + 1) * 512;

#define GSTAGE(buf, k0)                            \
  do {                                             \
    f16* s_ = sm + (buf) * 8192;                   \
    gload16(gA0 + (k0), s_ + lds0);                \
    gload16(gA1 + (k0), s_ + lds1);                \
    gload16(gB0 + (k0), s_ + 4096 + lds0);         \
    gload16(gB1 + (k0), s_ + 4096 + lds1);         \
  } while (0)

  GSTAGE(0, 0);
  __syncthreads();
#pragma unroll 2
  for (int ks = 0; ks < 32; ++ks) {
    const int cur = ks & 1;
    if (ks < 31) GSTAGE(cur ^ 1, (ks + 1) * 32);
    const f16* bA = sm + cur * 8192;
    const f16* bB = bA + 4096;
    f16x8 af[4], bf[4];
#pragma unroll
    for (int m = 0; m < 4; ++m) {
      int r = wr * 64 + m * 16 + cL;
      af[m] = *(const f16x8*)&bA[r * 32 + ((g ^ (r & 3)) << 3)];
    }
#pragma unroll
    for (int n = 0; n < 4; ++n) {
      int r = wc * 64 + n * 16 + cL;
      bf[n] = *(const f16x8*)&bB[r * 32 + ((g ^ (r & 3)) << 3)];
    }
#pragma unroll
    for (int m = 0; m < 4; ++m)
#pragma unroll
      for (int n = 0; n < 4; ++n) acc[m][n] = MFMA16(af[m], bf[n], acc[m][n]);
    __syncthreads();
  }
#undef GSTAGE
}

// Output projection -> fp32 d_out
__global__ __launch_bounds__(256) void gemm_out_kernel(const f16* __restrict__ Oh,
                                                       const f16* __restrict__ WoT,
                                                       float* __restrict__ out) {
  __shared__ __align__(16) f16 sm[2][8192];
  int mrow = blockIdx.y * 128, ncol0 = blockIdx.x * 128;
  f32x4 acc[4][4] = {};
  gemm128_core(Oh, WoT, mrow, ncol0, &sm[0][0], acc);
  int lane = threadIdx.x & 63, w = threadIdx.x >> 6;
  int cL = lane & 15, g = lane >> 4;
  int wr = w >> 1, wc = w & 1;
#pragma unroll
  for (int m = 0; m < 4; ++m)
#pragma unroll
    for (int n = 0; n < 4; ++n)
#pragma unroll
      for (int r = 0; r < 4; ++r) {
        int tt = mrow + wr * 64 + m * 16 + g * 4 + r;
        out[(size_t)tt * 1024 + ncol0 + wc * 64 + n * 16 + cL] = acc[m][n][r];
      }
}

// ---------------------------------------------------------------- attention (R12/R14)
__global__ __launch_bounds__(512, 2) void attn_kernel(const f16* __restrict__ Qh,
                                                      const f16* __restrict__ Kh,
                                                      const f16* __restrict__ Vt,
                                                      const f16* __restrict__ bias_rel,
                                                      f16* __restrict__ Oh) {
  __shared__ __align__(16) f16 sKV[2][4][8192];  // [group][buf][K 4096 | V 4096]
  __shared__ __align__(16) f16 sB[2176];         // bias slice (f16, log2e-scaled)
  const int p = blockIdx.x;
  const int L = ((p & 7) << 6) + (p >> 3);
  const int bh = L >> 4;
  const int qt = (L & 15) << 7;
  const int h = bh & 15, b = bh >> 4;
  int t = threadIdx.x;
  int lane = t & 63, wave = t >> 6;
  const int gr = wave >> 2, sw = wave & 3;
  int lo5 = lane & 31, hi = lane >> 5;
  const size_t bhS = (size_t)bh * 2048;
  const int qrow = qt + sw * 32 + lo5;  // this lane's q-row (col of S^T/O^T)

  const f16* qp = Qh + (bhS + qrow) * 64 + hi * 8;
  f16x8 qf[4];
#pragma unroll
  for (int m = 0; m < 4; ++m) qf[m] = *(const f16x8*)(qp + 16 * m);

  float cpos = (float)bias_rel[(size_t)h * 4096 + 4095];  // rp = +2047
  float cneg = (float)bias_rel[(size_t)h * 4096 + 1];     // rp = -2047

#pragma unroll
  for (int m = 0; m < 4; ++m) KEEPV8(qf[m]);
  asm volatile("" ::"v"(cpos), "v"(cneg));

  {
    const float4* gB = (const float4*)(bias_rel + (size_t)h * 4096 + 1920 - qt);
    for (int i = t; i < 272; i += 512) ((float4*)sB)[i] = gB[i];
  }

  const int tg = t & 255;
  const int rK0 = tg >> 3, ccK0 = ((tg & 7) ^ (rK0 & 7)) << 3;
  const int rK1 = rK0 + 32, ccK1 = ((tg & 7) ^ (rK1 & 7)) << 3;
  const f16* gK0 = Kh + (bhS + rK0) * 64 + ccK0;
  const f16* gK1 = Kh + (bhS + rK1) * 64 + ccK1;
  const f16* gV0 = Vt + ((size_t)bh * 64 + rK0) * 2048 + ccK0;
  const f16* gV1 = Vt + ((size_t)bh * 64 + rK1) * 2048 + ccK1;
  const int ldsA = sw * 512, ldsB = sw * 512 + 2048;

#define ASTAGE(buf, key0)                           \
  do {                                              \
    f16* s_ = &sKV[gr][buf][0];                     \
    gload16(gK0 + (size_t)(key0) * 64, s_ + ldsA);  \
    gload16(gK1 + (size_t)(key0) * 64, s_ + ldsB);  \
    gload16(gV0 + (key0), s_ + 4096 + ldsA);        \
    gload16(gV1 + (key0), s_ + 4096 + ldsB);        \
  } while (0)

  f32x16 o0 = {}, o1 = {};
  float m_ = -INFINITY, lsum = 0.f;
  const int sw7 = lo5 & 7;
  const int kbase = gr << 10;

  auto qk = [&](const f16* kb, f32x16& s0, f32x16& s1) {
    const f16* kr0 = kb + lo5 * 64;
    const f16* kr1 = kb + (32 + lo5) * 64;
#pragma unroll
    for (int m = 0; m < 4; ++m) {
      int c = ((2 * m + hi) ^ sw7) << 3;
      s0 = MFMA32(*(const f16x8*)(kr0 + c), qf[m], s0);
      s1 = MFMA32(*(const f16x8*)(kr1 + c), qf[m], s1);
    }
  };
  auto rowmax = [&](const f32x16& a, const f32x16& bvec) -> float {
    float tm[16];
#pragma unroll
    for (int i = 0; i < 16; ++i) tm[i] = fmaxf(a[i], bvec[i]);
#pragma unroll
    for (int s2 = 8; s2; s2 >>= 1)
#pragma unroll
      for (int i = 0; i < 8; ++i)
        if (i < s2) tm[i] = fmaxf(tm[i], tm[i + s2]);
    return tm[0];
  };
  auto softpack = [&](const f32x16& s0, const f32x16& s1, f16x8& b0, f16x8& b1, f16x8& b2,
                      f16x8& b3) -> float {
    float pr[16];
    u32 w0, w1, w2, w3, w4, w5, w6, w7;
#pragma unroll
    for (int i = 0; i < 16; ++i) pr[i] = EXP2(s0[i] - m_);
    w0 = pk2(pr[0], pr[1]);   w1 = pk2(pr[2], pr[3]);
    w2 = pk2(pr[4], pr[5]);   w3 = pk2(pr[6], pr[7]);
    w4 = pk2(pr[8], pr[9]);   w5 = pk2(pr[10], pr[11]);
    w6 = pk2(pr[12], pr[13]); w7 = pk2(pr[14], pr[15]);
#pragma unroll
    for (int s2 = 8; s2; s2 >>= 1)
#pragma unroll
      for (int i = 0; i < 8; ++i)
        if (i < s2) pr[i] += pr[i + s2];
    float ls = pr[0];
    swap32(w0, w2); swap32(w1, w3); swap32(w4, w6); swap32(w5, w7);
    b0 = __builtin_bit_cast(f16x8, (u32x4){w0, w1, w2, w3});
    b1 = __builtin_bit_cast(f16x8, (u32x4){w4, w5, w6, w7});
#pragma unroll
    for (int i = 0; i < 16; ++i) pr[i] = EXP2(s1[i] - m_);
    w0 = pk2(pr[0], pr[1]);   w1 = pk2(pr[2], pr[3]);
    w2 = pk2(pr[4], pr[5]);   w3 = pk2(pr[6], pr[7]);
    w4 = pk2(pr[8], pr[9]);   w5 = pk2(pr[10], pr[11]);
    w6 = pk2(pr[12], pr[13]); w7 = pk2(pr[14], pr[15]);
#pragma unroll
    for (int s2 = 8; s2; s2 >>= 1)
#pragma unroll
      for (int i = 0; i < 8; ++i)
        if (i < s2) pr[i] += pr[i + s2];
    ls += pr[0];
    swap32(w0, w2); swap32(w1, w3); swap32(w4, w6); swap32(w5, w7);
    b2 = __builtin_bit_cast(f16x8, (u32x4){w0, w1, w2, w3});
    b3 = __builtin_bit_cast(f16x8, (u32x4){w4, w5, w6, w7});
    return ls;
  };
  auto pv = [&](const f16* vb, const f16x8& b0, const f16x8& b1, const f16x8& b2,
                const f16x8& b3) {
    const f16* vr0 = vb + lo5 * 64;
    const f16* vr1 = vb + (32 + lo5) * 64;
    {
      int c = ((0 + hi) ^ sw7) << 3;
      o0 = MFMA32(*(const f16x8*)(vr0 + c), b0, o0);
      o1 = MFMA32(*(const f16x8*)(vr1 + c), b0, o1);
    }
    {
      int c = ((2 + hi) ^ sw7) << 3;
      o0 = MFMA32(*(const f16x8*)(vr0 + c), b1, o0);
      o1 = MFMA32(*(const f16x8*)(vr1 + c), b1, o1);
    }
    {
      int c = ((4 + hi) ^ sw7) << 3;
      o0 = MFMA32(*(const f16x8*)(vr0 + c), b2, o0);
      o1 = MFMA32(*(const f16x8*)(vr1 + c), b2, o1);
    }
    {
      int c = ((6 + hi) ^ sw7) << 3;
      o0 = MFMA32(*(const f16x8*)(vr0 + c), b3, o0);
      o1 = MFMA32(*(const f16x8*)(vr1 + c), b3, o1);
    }
  };
  auto biasinit = [&](int key0, f32x16& s0, f32x16& s1) {
    const int dkt = key0 - qt;
    if (dkt >= 256 || dkt <= -192) {
      float c = (dkt > 0) ? cpos : cneg;
#pragma unroll
      for (int i = 0; i < 16; ++i) { s0[i] = c; s1[i] = c; }
    } else {
      const int bb = key0 + 4 * hi - sw * 32 - lo5 + 128;
#pragma unroll
      for (int i = 0; i < 16; ++i) {
        int pat = (i & 3) + 8 * (i >> 2);
        s0[i] = (float)sB[bb + pat];
        s1[i] = (float)sB[bb + 32 + pat];
      }
    }
  };

  ASTAGE(0, kbase);
  ASTAGE(1, kbase + 64);
  asm volatile("s_waitcnt lgkmcnt(0)" ::: "memory");

  for (int pp = 0; pp < 8; ++pp) {
    asm volatile("s_waitcnt vmcnt(0)" ::: "memory");
    __builtin_amdgcn_s_barrier();
    if (pp < 7) {
      ASTAGE((2 * pp + 2) & 3, kbase + (2 * pp + 2) * 64);
      ASTAGE((2 * pp + 3) & 3, kbase + (2 * pp + 3) * 64);
    }
    const int keyA = kbase + 2 * pp * 64;
    const f16* bufA = &sKV[gr][(2 * pp) & 3][0];
    const f16* bufB = &sKV[gr][(2 * pp + 1) & 3][0];

    f32x16 saA0, saA1, saB0, saB1;
    biasinit(keyA, saA0, saA1);
    biasinit(keyA + 64, saB0, saB1);
    __builtin_amdgcn_s_setprio(1);
    qk(bufA, saA0, saA1);
    qk(bufB, saB0, saB1);
    __builtin_amdgcn_s_setprio(0);

    float mx = fmaxf(rowmax(saA0, saA1), rowmax(saB0, saB1));
    mx = fmaxf(mx, __shfl_xor(mx, 32));
    if (__any(mx > m_ + 8.f)) {
      float mn = fmaxf(m_, mx);
      float corr = EXP2(m_ - mn);
      lsum *= corr;
      m_ = mn;
#pragma unroll
      for (int i = 0; i < 16; ++i) { o0[i] *= corr; o1[i] *= corr; }
    }

    f16x8 f0, f1, f2, f3;
    lsum += softpack(saA0, saA1, f0, f1, f2, f3);
    __builtin_amdgcn_s_setprio(1);
    pv(bufA + 4096, f0, f1, f2, f3);
    __builtin_amdgcn_s_setprio(0);
    lsum += softpack(saB0, saB1, f0, f1, f2, f3);
    __builtin_amdgcn_s_setprio(1);
    pv(bufB + 4096, f0, f1, f2, f3);
    __builtin_amdgcn_s_setprio(0);
  }
#undef ASTAGE

  __syncthreads();
  float* sX = (float*)&sKV[0][0][0];
  const int slot = (sw * 64 + lane) * 35;
  if (gr == 1) {
#pragma unroll
    for (int i = 0; i < 16; ++i) {
      sX[slot + i] = o0[i];
      sX[slot + 16 + i] = o1[i];
    }
    sX[slot + 32] = m_;
    sX[slot + 33] = lsum;
  }
  __syncthreads();
  if (gr == 0) {
    float m2 = sX[slot + 32], l2 = sX[slot + 33];
    float mn = fmaxf(m_, m2);
    float c1 = EXP2(m_ - mn), c2 = EXP2(m2 - mn);
    float s = lsum * c1 + l2 * c2;
    s += __shfl_xor(s, 32);
    float inv = 1.0f / s;
    size_t base = ((size_t)b * 2048 + qrow) * 1024 + h * 64 + 4 * hi;
#pragma unroll
    for (int rq = 0; rq < 4; ++rq) {
      f16x4 v0, v1;
#pragma unroll
      for (int j = 0; j < 4; ++j) {
        v0[j] = (f16)((o0[rq * 4 + j] * c1 + sX[slot + rq * 4 + j] * c2) * inv);
        v1[j] = (f16)((o1[rq * 4 + j] * c1 + sX[slot + 16 + rq * 4 + j] * c2) * inv);
      }
      *(f16x4*)&Oh[base + 8 * rq] = v0;
      *(f16x4*)&Oh[base + 32 + 8 * rq] = v1;
    }
  }
}

// ---------------------------------------------------------------- launch

extern "C" void kernel_launch(void* const* d_in, const int* in_sizes, int n_in,
                              void* d_out, int out_size, void* d_ws, size_t ws_size,
                              hipStream_t stream) {
  const float* X = (const float*)d_in[0];
  const float* Wq = (const float*)d_in[1];
  const float* Wk = (const float*)d_in[2];
  const float* Wv = (const float*)d_in[3];
  const float* Wo = (const float*)d_in[4];
  const float* relb = (const float*)d_in[5];

  const size_t MB8 = (size_t)8 << 20;
  if (ws_size < 6 * MB8 + (1 << 19)) return;

  char* ws = (char*)d_ws;
  f16* Xh = (f16*)(ws + 0 * MB8);
  f16* Wt = (f16*)(ws + 1 * MB8);
  f16* Qh = (f16*)(ws + 2 * MB8);
  f16* Kh = (f16*)(ws + 3 * MB8);
  f16* Vt = (f16*)(ws + 4 * MB8);
  f16* Oh = (f16*)(ws + 5 * MB8);
  f16* brel = (f16*)(ws + 6 * MB8);  // [16][4096] f16, log2e-scaled

  prep_kernel<<<dim3(32, 32, 6), dim3(32, 8), 0, stream>>>(X, Wq, Wk, Wv, Wo, relb,
                                                           (f16x4*)Xh, Wt, brel);
  gemm_qkv256_kernel<<<dim3(192), dim3(512), 0, stream>>>(Xh, Wt, Qh, Kh, Vt);
  attn_kernel<<<dim3(512), dim3(512), 0, stream>>>(Qh, Kh, Vt, brel, Oh);
  gemm_out_kernel<<<dim3(8, 32), dim3(256), 0, stream>>>(Oh, Wt + (size_t)3072 * 1024,
                                                         (float*)d_out);
}

// Round 17
// 136.137 us; speedup vs baseline: 1.6841x; 1.6841x over previous
//
#include <hip/hip_runtime.h>
#include <math.h>

// B=2, S=2048, D=1024, H=16, DK=64, NUM_BUCKETS=32, MAX_DIST=128, SM_SCALE=0.25
// Softmax in log2 domain: Wq pre-scaled by 0.25*log2(e), bias table pre-scaled by log2(e).
// attn: 32x32x16 MFMA, swapped QK^T; in-register P redistribution (cvt_pkrtz+permlane32);
// SPLIT-K (2 groups x 4 waves) + PAIR-ITERATION: one barrier per 2 tiles, 4 LDS buffers,
// QK of both tiles issued back-to-back (4 indep MFMA chains), joint defer-max, shared
// o-accumulators. Online-softmax merge across groups via LDS. V produced row-major by
// gemm_qkv (coalesced) and transposed by a dedicated LDS-tile kernel.
// [R16 post-mortem: 256^2 8-phase GEMM port abandoned — compiler pinned VGPR at 128 and
// spilled the 128-VGPR accumulator block (WRITE_SIZE 212MB); launch_bounds didn't lift it.
// This file is the session-best verified configuration (R12, 136.2 us).]

typedef _Float16 f16;
typedef _Float16 f16x4 __attribute__((ext_vector_type(4)));
typedef _Float16 f16x8 __attribute__((ext_vector_type(8)));
typedef float f32x4 __attribute__((ext_vector_type(4)));
typedef float f32x16 __attribute__((ext_vector_type(16)));
typedef unsigned int u32;
typedef u32 u32x4 __attribute__((ext_vector_type(4)));

#define MFMA16(a, b, c) __builtin_amdgcn_mfma_f32_16x16x32_f16((a), (b), (c), 0, 0, 0)
#define MFMA32(a, b, c) __builtin_amdgcn_mfma_f32_32x32x16_f16((a), (b), (c), 0, 0, 0)

static __device__ __forceinline__ float EXP2(float x) {
  float r;
  asm("v_exp_f32 %0, %1" : "=v"(r) : "v"(x));
  return r;
}

// pack two f32 -> f16x2 in a u32 (RTZ)
static __device__ __forceinline__ u32 pk2(float a, float b) {
  return __builtin_bit_cast(u32, __builtin_amdgcn_cvt_pkrtz(a, b));
}
// exchange: a.hi(lanes32-63) <- b.lo(lanes0-31 old), b.lo <- a.hi(old)
static __device__ __forceinline__ void swap32(u32& a, u32& b) {
  asm volatile("v_permlane32_swap_b32 %0, %1" : "+v"(a), "+v"(b));
}

// force a loaded value resident NOW (retire its vmcnt in the prologue so the
// loop's counted waits see only staging loads)
#define KEEPV8(v8)                                                        \
  do {                                                                    \
    u32x4 _t = __builtin_bit_cast(u32x4, (v8));                           \
    asm volatile("" ::"v"(_t[0]), "v"(_t[1]), "v"(_t[2]), "v"(_t[3]));    \
  } while (0)

// async global->LDS, 16B per lane; lds base must be wave-uniform (HW adds lane*16)
__device__ __forceinline__ void gload16(const f16* g, f16* l) {
  __builtin_amdgcn_global_load_lds(
      (const __attribute__((address_space(1))) void*)g,
      (__attribute__((address_space(3))) void*)l, 16, 0, 0);
}

// ---------------------------------------------------------------- prep kernel
// grid (32,32,6), block (32,8):
//  z<4 : W[k][n] -> Wt[z*1024+n][k] f16 (Wq scaled by 0.25*log2e)
//  z==4: T5 bias table (blocks with blockIdx.x<8), [h][4096], idx rp+2048, *log2e, f16
//  z==5: X fp32 -> f16 (4 float4 per thread)
__global__ void prep_kernel(const float* __restrict__ X, const float* __restrict__ w0,
                            const float* __restrict__ w1, const float* __restrict__ w2,
                            const float* __restrict__ w3, const float* __restrict__ relb,
                            f16x4* __restrict__ xh, f16* __restrict__ wt,
                            f16* __restrict__ bias_rel) {
  const int z = blockIdx.z;
  const int tx = threadIdx.x, ty = threadIdx.y;
  if (z < 4) {
    const float* w = (z == 0) ? w0 : (z == 1) ? w1 : (z == 2) ? w2 : w3;
    float sc = (z == 0) ? 0.36067376022224085f : 1.0f;  // 0.25 * log2(e)
    __shared__ float tile[32][33];
    int kt = blockIdx.x * 32, nt = blockIdx.y * 32;
#pragma unroll
    for (int i = 0; i < 4; ++i)
      tile[ty + i * 8][tx] = w[(size_t)(kt + ty + i * 8) * 1024 + nt + tx];
    __syncthreads();
#pragma unroll
    for (int i = 0; i < 4; ++i)
      wt[((size_t)z * 1024 + nt + ty + i * 8) * 1024 + kt + tx] =
          (f16)(tile[tx][ty + i * 8] * sc);
  } else if (z == 4) {
    if (blockIdx.x >= 8) return;
    int idx = (blockIdx.x * 32 + blockIdx.y) * 256 + ty * 32 + tx;  // 0..65535
    int h = idx >> 12;
    int r = idx & 4095;
    int rp = r - 2048;
    if (rp < -2047) rp = -2047;
    int bucket = (rp > 0) ? 16 : 0;
    int rpa = (rp < 0) ? -rp : rp;
    if (rpa < 8) {
      bucket += rpa;
    } else {
      int large = 8 + (int)(logf((float)rpa / 8.0f) / logf(16.0f) * 8.0f);
      bucket += (large < 15) ? large : 15;
    }
    bias_rel[idx] = (f16)(relb[bucket * 16 + h] * 1.4426950408889634f);
  } else {
    const float4* x4 = (const float4*)X;
    int i = (blockIdx.x * 32 + blockIdx.y) * 256 + ty * 32 + tx;
#pragma unroll
    for (int rep = 0; rep < 4; ++rep, i += 262144) {
      float4 v = x4[i];
      f16x4 o;
      o[0] = (f16)v.x; o[1] = (f16)v.y; o[2] = (f16)v.z; o[3] = (f16)v.w;
      xh[i] = o;
    }
  }
}

// V [bh][s][dk] (row-major, coalesced producer) -> Vt [bh][dk][s]
__global__ void transpose_v_kernel(const f16* __restrict__ vin, f16* __restrict__ vout) {
  __shared__ f16 tile[32][33];
  int bh = blockIdx.z;
  int s0 = blockIdx.x * 32, d0 = blockIdx.y * 32;
  int tx = threadIdx.x, ty = threadIdx.y;
  const f16* src = vin + ((size_t)bh * 2048 + s0) * 64 + d0;
#pragma unroll
  for (int i = 0; i < 4; ++i) tile[ty + i * 8][tx] = src[(size_t)(ty + i * 8) * 64 + tx];
  __syncthreads();
  f16* dst = vout + ((size_t)bh * 64 + d0) * 2048 + s0;
#pragma unroll
  for (int i = 0; i < 4; ++i) dst[(size_t)(ty + i * 8) * 2048 + tx] = tile[tx][ty + i * 8];
}

// ---------------------------------------------------------------- GEMM 128x128, BK=32
__device__ __forceinline__ void gemm128_core(const f16* __restrict__ A, const f16* __restrict__ Bt,
                                             int mrow, int ncol0, f16* sm /*[2][8192]*/,
                                             f32x4 acc[4][4]) {
  const int t = threadIdx.x;
  const int lane = t & 63, w = t >> 6;
  const int cL = lane & 15, g = lane >> 4;
  const int wr = w >> 1, wc = w & 1;

  const int c0 = w * 128 + lane;
  const int c1 = c0 + 64;
  const int rA0 = c0 >> 2, kA0 = ((c0 & 3) ^ (rA0 & 3)) << 3;
  const int rA1 = c1 >> 2, kA1 = ((c1 & 3) ^ (rA1 & 3)) << 3;
  const f16* gA0 = A + (size_t)(mrow + rA0) * 1024 + kA0;
  const f16* gA1 = A + (size_t)(mrow + rA1) * 1024 + kA1;
  const f16* gB0 = Bt + (size_t)(ncol0 + rA0) * 1024 + kA0;
  const f16* gB1 = Bt + (size_t)(ncol0 + rA1) * 1024 + kA1;
  const int lds0 = (w * 2) * 512, lds1 = (w * 2 + 1) * 512;

#define GSTAGE(buf, k0)                            \
  do {                                             \
    f16* s_ = sm + (buf) * 8192;                   \
    gload16(gA0 + (k0), s_ + lds0);                \
    gload16(gA1 + (k0), s_ + lds1);                \
    gload16(gB0 + (k0), s_ + 4096 + lds0);         \
    gload16(gB1 + (k0), s_ + 4096 + lds1);         \
  } while (0)

  GSTAGE(0, 0);
  __syncthreads();
#pragma unroll 2
  for (int ks = 0; ks < 32; ++ks) {
    const int cur = ks & 1;
    if (ks < 31) GSTAGE(cur ^ 1, (ks + 1) * 32);
    const f16* bA = sm + cur * 8192;
    const f16* bB = bA + 4096;
    f16x8 af[4], bf[4];
#pragma unroll
    for (int m = 0; m < 4; ++m) {
      int r = wr * 64 + m * 16 + cL;
      af[m] = *(const f16x8*)&bA[r * 32 + ((g ^ (r & 3)) << 3)];
    }
#pragma unroll
    for (int n = 0; n < 4; ++n) {
      int r = wc * 64 + n * 16 + cL;
      bf[n] = *(const f16x8*)&bB[r * 32 + ((g ^ (r & 3)) << 3)];
    }
#pragma unroll
    for (int m = 0; m < 4; ++m)
#pragma unroll
      for (int n = 0; n < 4; ++n) acc[m][n] = MFMA16(af[m], bf[n], acc[m][n]);
    __syncthreads();
  }
#undef GSTAGE
}

// QKV projection -> Q,K,V all [b][h][s][dk] row-major (V transposed afterwards)
__global__ __launch_bounds__(256) void gemm_qkv_kernel(const f16* __restrict__ Xh,
                                                       const f16* __restrict__ Wt,
                                                       f16* __restrict__ Qh,
                                                       f16* __restrict__ Kh,
                                                       f16* __restrict__ Vrow) {
  __shared__ __align__(16) f16 sm[2][8192];
  int mrow = blockIdx.y * 128, ncol0 = blockIdx.x * 128;
  f32x4 acc[4][4] = {};
  gemm128_core(Xh, Wt, mrow, ncol0, &sm[0][0], acc);
  int lane = threadIdx.x & 63, w = threadIdx.x >> 6;
  int cL = lane & 15, g = lane >> 4;
  int wr = w >> 1, wc = w & 1;
  int which = (ncol0 + wc * 64) >> 10;
  f16* dst = (which == 0) ? Qh : (which == 1) ? Kh : Vrow;
#pragma unroll
  for (int m = 0; m < 4; ++m) {
#pragma unroll
    for (int n = 0; n < 4; ++n) {
#pragma unroll
      for (int r = 0; r < 4; ++r) {
        int tt = mrow + wr * 64 + m * 16 + g * 4 + r;
        int b = tt >> 11, s = tt & 2047;
        int col = (ncol0 + wc * 64 + n * 16 + cL) & 1023;
        int hh = col >> 6, dk = col & 63;
        dst[(((size_t)b * 16 + hh) * 2048 + s) * 64 + dk] = (f16)acc[m][n][r];
      }
    }
  }
}

// Output projection -> fp32 d_out
__global__ __launch_bounds__(256) void gemm_out_kernel(const f16* __restrict__ Oh,
                                                       const f16* __restrict__ WoT,
                                                       float* __restrict__ out) {
  __shared__ __align__(16) f16 sm[2][8192];
  int mrow = blockIdx.y * 128, ncol0 = blockIdx.x * 128;
  f32x4 acc[4][4] = {};
  gemm128_core(Oh, WoT, mrow, ncol0, &sm[0][0], acc);
  int lane = threadIdx.x & 63, w = threadIdx.x >> 6;
  int cL = lane & 15, g = lane >> 4;
  int wr = w >> 1, wc = w & 1;
#pragma unroll
  for (int m = 0; m < 4; ++m)
#pragma unroll
    for (int n = 0; n < 4; ++n)
#pragma unroll
      for (int r = 0; r < 4; ++r) {
        int tt = mrow + wr * 64 + m * 16 + g * 4 + r;
        out[(size_t)tt * 1024 + ncol0 + wc * 64 + n * 16 + cL] = acc[m][n][r];
      }
}

// ---------------------------------------------------------------- attention
// 1-D grid 512 blocks, XCD-swizzled: L = (bid%8)*64 + bid/8; bh = L/16, qt = (L%16)*128.
// 512 threads = 8 waves = 2 groups x 4. Group g: keys [g*1024, +1024) as 8 PAIRS of
// 64-key tiles; 4 LDS buffers/group; per pair: vmcnt(0)-own -> barrier -> stage next
// pair -> biasA/B + QK-A + QK-B (4 indep MFMA chains) -> joint defer-max ->
// softpackA/PV-A -> softpackB/PV-B into SHARED o-accumulators. Epilogue merges the
// two groups' (o, m, lsum) through LDS with online-softmax rescaling.
__global__ __launch_bounds__(512) void attn_kernel(const f16* __restrict__ Qh,
                                                   const f16* __restrict__ Kh,
                                                   const f16* __restrict__ Vt,
                                                   const f16* __restrict__ bias_rel,
                                                   f16* __restrict__ Oh) {
  __shared__ __align__(16) f16 sKV[2][4][8192];  // [group][buf][K 4096 | V 4096]
  __shared__ __align__(16) f16 sB[2176];         // bias slice (f16, log2e-scaled)
  const int p = blockIdx.x;
  const int L = ((p & 7) << 6) + (p >> 3);
  const int bh = L >> 4;
  const int qt = (L & 15) << 7;
  const int h = bh & 15, b = bh >> 4;
  int t = threadIdx.x;
  int lane = t & 63, wave = t >> 6;
  const int gr = wave >> 2, sw = wave & 3;
  int lo5 = lane & 31, hi = lane >> 5;
  const size_t bhS = (size_t)bh * 2048;
  const int qrow = qt + sw * 32 + lo5;  // this lane's q-row (col of S^T/O^T)

  // Q B-fragments: qf[m] = Q[qrow][16m + 8hi .. +7] (Q pre-scaled by 0.25*log2e)
  const f16* qp = Qh + (bhS + qrow) * 64 + hi * 8;
  f16x8 qf[4];
#pragma unroll
  for (int m = 0; m < 4; ++m) qf[m] = *(const f16x8*)(qp + 16 * m);

  // far-tile constants: bucket saturates for |rp| >= 91
  float cpos = (float)bias_rel[(size_t)h * 4096 + 4095];  // rp = +2047
  float cneg = (float)bias_rel[(size_t)h * 4096 + 1];     // rp = -2047

  // retire the above loads' vmcnt NOW (before any pipelined stage is issued)
#pragma unroll
  for (int m = 0; m < 4; ++m) KEEPV8(qf[m]);
  asm volatile("" ::"v"(cpos), "v"(cneg));

  // stage bias slice: sB[j] = bias_rel[h*4096 + 1920 - qt + j]; bias(q,k)=sB[k-(q-qt)+128]
  {
    const float4* gB = (const float4*)(bias_rel + (size_t)h * 4096 + 1920 - qt);
    for (int i = t; i < 272; i += 512) ((float4*)sB)[i] = gB[i];
  }

  // K/V staging (per group; 256 threads): pre-swizzled global src, linear LDS dest
  const int tg = t & 255;
  const int rK0 = tg >> 3, ccK0 = ((tg & 7) ^ (rK0 & 7)) << 3;
  const int rK1 = rK0 + 32, ccK1 = ((tg & 7) ^ (rK1 & 7)) << 3;
  const f16* gK0 = Kh + (bhS + rK0) * 64 + ccK0;
  const f16* gK1 = Kh + (bhS + rK1) * 64 + ccK1;
  const f16* gV0 = Vt + ((size_t)bh * 64 + rK0) * 2048 + ccK0;
  const f16* gV1 = Vt + ((size_t)bh * 64 + rK1) * 2048 + ccK1;
  const int ldsA = sw * 512, ldsB = sw * 512 + 2048;

#define ASTAGE(buf, key0)                           \
  do {                                              \
    f16* s_ = &sKV[gr][buf][0];                     \
    gload16(gK0 + (size_t)(key0) * 64, s_ + ldsA);  \
    gload16(gK1 + (size_t)(key0) * 64, s_ + ldsB);  \
    gload16(gV0 + (key0), s_ + 4096 + ldsA);        \
    gload16(gV1 + (key0), s_ + 4096 + ldsB);        \
  } while (0)

  f32x16 o0 = {}, o1 = {};  // O^T[dk][q=lo5]; o0: dk 0-31, o1: dk 32-63
  float m_ = -INFINITY, lsum = 0.f;
  const int sw7 = lo5 & 7;
  const int kbase = gr << 10;  // group key offset

  // ---- helpers (register-only; inlined) ----
  auto qk = [&](const f16* kb, f32x16& s0, f32x16& s1) {
    const f16* kr0 = kb + lo5 * 64;
    const f16* kr1 = kb + (32 + lo5) * 64;
#pragma unroll
    for (int m = 0; m < 4; ++m) {
      int c = ((2 * m + hi) ^ sw7) << 3;
      s0 = MFMA32(*(const f16x8*)(kr0 + c), qf[m], s0);
      s1 = MFMA32(*(const f16x8*)(kr1 + c), qf[m], s1);
    }
  };
  auto rowmax = [&](const f32x16& a, const f32x16& bvec) -> float {
    float tm[16];
#pragma unroll
    for (int i = 0; i < 16; ++i) tm[i] = fmaxf(a[i], bvec[i]);
#pragma unroll
    for (int s2 = 8; s2; s2 >>= 1)
#pragma unroll
      for (int i = 0; i < 8; ++i)
        if (i < s2) tm[i] = fmaxf(tm[i], tm[i + s2]);
    return tm[0];
  };
  auto softpack = [&](const f32x16& s0, const f32x16& s1, f16x8& b0, f16x8& b1, f16x8& b2,
                      f16x8& b3) -> float {
    float pr[16];
    u32 w0, w1, w2, w3, w4, w5, w6, w7;
#pragma unroll
    for (int i = 0; i < 16; ++i) pr[i] = EXP2(s0[i] - m_);
    w0 = pk2(pr[0], pr[1]);   w1 = pk2(pr[2], pr[3]);
    w2 = pk2(pr[4], pr[5]);   w3 = pk2(pr[6], pr[7]);
    w4 = pk2(pr[8], pr[9]);   w5 = pk2(pr[10], pr[11]);
    w6 = pk2(pr[12], pr[13]); w7 = pk2(pr[14], pr[15]);
#pragma unroll
    for (int s2 = 8; s2; s2 >>= 1)
#pragma unroll
      for (int i = 0; i < 8; ++i)
        if (i < s2) pr[i] += pr[i + s2];
    float ls = pr[0];
    swap32(w0, w2); swap32(w1, w3); swap32(w4, w6); swap32(w5, w7);
    b0 = __builtin_bit_cast(f16x8, (u32x4){w0, w1, w2, w3});
    b1 = __builtin_bit_cast(f16x8, (u32x4){w4, w5, w6, w7});
#pragma unroll
    for (int i = 0; i < 16; ++i) pr[i] = EXP2(s1[i] - m_);
    w0 = pk2(pr[0], pr[1]);   w1 = pk2(pr[2], pr[3]);
    w2 = pk2(pr[4], pr[5]);   w3 = pk2(pr[6], pr[7]);
    w4 = pk2(pr[8], pr[9]);   w5 = pk2(pr[10], pr[11]);
    w6 = pk2(pr[12], pr[13]); w7 = pk2(pr[14], pr[15]);
#pragma unroll
    for (int s2 = 8; s2; s2 >>= 1)
#pragma unroll
      for (int i = 0; i < 8; ++i)
        if (i < s2) pr[i] += pr[i + s2];
    ls += pr[0];
    swap32(w0, w2); swap32(w1, w3); swap32(w4, w6); swap32(w5, w7);
    b2 = __builtin_bit_cast(f16x8, (u32x4){w0, w1, w2, w3});
    b3 = __builtin_bit_cast(f16x8, (u32x4){w4, w5, w6, w7});
    return ls;
  };
  auto pv = [&](const f16* vb, const f16x8& b0, const f16x8& b1, const f16x8& b2,
                const f16x8& b3) {
    const f16* vr0 = vb + lo5 * 64;
    const f16* vr1 = vb + (32 + lo5) * 64;
    {
      int c = ((0 + hi) ^ sw7) << 3;
      o0 = MFMA32(*(const f16x8*)(vr0 + c), b0, o0);
      o1 = MFMA32(*(const f16x8*)(vr1 + c), b0, o1);
    }
    {
      int c = ((2 + hi) ^ sw7) << 3;
      o0 = MFMA32(*(const f16x8*)(vr0 + c), b1, o0);
      o1 = MFMA32(*(const f16x8*)(vr1 + c), b1, o1);
    }
    {
      int c = ((4 + hi) ^ sw7) << 3;
      o0 = MFMA32(*(const f16x8*)(vr0 + c), b2, o0);
      o1 = MFMA32(*(const f16x8*)(vr1 + c), b2, o1);
    }
    {
      int c = ((6 + hi) ^ sw7) << 3;
      o0 = MFMA32(*(const f16x8*)(vr0 + c), b3, o0);
      o1 = MFMA32(*(const f16x8*)(vr1 + c), b3, o1);
    }
  };
  auto biasinit = [&](int key0, f32x16& s0, f32x16& s1) {
    const int dkt = key0 - qt;
    if (dkt >= 256 || dkt <= -192) {
      float c = (dkt > 0) ? cpos : cneg;
#pragma unroll
      for (int i = 0; i < 16; ++i) { s0[i] = c; s1[i] = c; }
    } else {
      const int bb = key0 + 4 * hi - sw * 32 - lo5 + 128;
#pragma unroll
      for (int i = 0; i < 16; ++i) {
        int pat = (i & 3) + 8 * (i >> 2);
        s0[i] = (float)sB[bb + pat];
        s1[i] = (float)sB[bb + 32 + pat];
      }
    }
  };

  // prologue: first pair in flight; drain sB ds_writes before first barrier
  ASTAGE(0, kbase);
  ASTAGE(1, kbase + 64);
  asm volatile("s_waitcnt lgkmcnt(0)" ::: "memory");

  for (int pp = 0; pp < 8; ++pp) {
    // own stages of this pair are the only outstanding VMEM; barrier publishes them
    asm volatile("s_waitcnt vmcnt(0)" ::: "memory");
    __builtin_amdgcn_s_barrier();
    if (pp < 7) {
      ASTAGE((2 * pp + 2) & 3, kbase + (2 * pp + 2) * 64);
      ASTAGE((2 * pp + 3) & 3, kbase + (2 * pp + 3) * 64);
    }
    const int keyA = kbase + 2 * pp * 64;
    const f16* bufA = &sKV[gr][(2 * pp) & 3][0];
    const f16* bufB = &sKV[gr][(2 * pp + 1) & 3][0];

    f32x16 saA0, saA1, saB0, saB1;
    biasinit(keyA, saA0, saA1);
    biasinit(keyA + 64, saB0, saB1);
    __builtin_amdgcn_s_setprio(1);
    qk(bufA, saA0, saA1);   // 4 independent MFMA chains across the pair
    qk(bufB, saB0, saB1);
    __builtin_amdgcn_s_setprio(0);

    float mx = fmaxf(rowmax(saA0, saA1), rowmax(saB0, saB1));
    mx = fmaxf(mx, __shfl_xor(mx, 32));
    if (__any(mx > m_ + 8.f)) {  // joint defer-max for the pair
      float mn = fmaxf(m_, mx);
      float corr = EXP2(m_ - mn);
      lsum *= corr;
      m_ = mn;
#pragma unroll
      for (int i = 0; i < 16; ++i) { o0[i] *= corr; o1[i] *= corr; }
    }

    f16x8 f0, f1, f2, f3;
    lsum += softpack(saA0, saA1, f0, f1, f2, f3);
    __builtin_amdgcn_s_setprio(1);
    pv(bufA + 4096, f0, f1, f2, f3);
    __builtin_amdgcn_s_setprio(0);
    lsum += softpack(saB0, saB1, f0, f1, f2, f3);  // reuse P-frag registers
    __builtin_amdgcn_s_setprio(1);
    pv(bufB + 4096, f0, f1, f2, f3);
    __builtin_amdgcn_s_setprio(0);
  }
#undef ASTAGE

  // ---- epilogue: merge the two key-halves across groups via LDS, then store
  __syncthreads();  // all compute done; sKV free for reuse
  float* sX = (float*)&sKV[0][0][0];
  const int slot = (sw * 64 + lane) * 35;  // stride 35 floats: conflict-free-ish
  if (gr == 1) {
#pragma unroll
    for (int i = 0; i < 16; ++i) {
      sX[slot + i] = o0[i];
      sX[slot + 16 + i] = o1[i];
    }
    sX[slot + 32] = m_;
    sX[slot + 33] = lsum;
  }
  __syncthreads();
  if (gr == 0) {
    float m2 = sX[slot + 32], l2 = sX[slot + 33];
    float mn = fmaxf(m_, m2);
    float c1 = EXP2(m_ - mn), c2 = EXP2(m2 - mn);
    float s = lsum * c1 + l2 * c2;
    s += __shfl_xor(s, 32);  // combine the two key-halves held by lanes l, l+32
    float inv = 1.0f / s;
    size_t base = ((size_t)b * 2048 + qrow) * 1024 + h * 64 + 4 * hi;
#pragma unroll
    for (int rq = 0; rq < 4; ++rq) {
      f16x4 v0, v1;
#pragma unroll
      for (int j = 0; j < 4; ++j) {
        v0[j] = (f16)((o0[rq * 4 + j] * c1 + sX[slot + rq * 4 + j] * c2) * inv);
        v1[j] = (f16)((o1[rq * 4 + j] * c1 + sX[slot + 16 + rq * 4 + j] * c2) * inv);
      }
      *(f16x4*)&Oh[base + 8 * rq] = v0;
      *(f16x4*)&Oh[base + 32 + 8 * rq] = v1;
    }
  }
}

// ---------------------------------------------------------------- launch

extern "C" void kernel_launch(void* const* d_in, const int* in_sizes, int n_in,
                              void* d_out, int out_size, void* d_ws, size_t ws_size,
                              hipStream_t stream) {
  const float* X = (const float*)d_in[0];
  const float* Wq = (const float*)d_in[1];
  const float* Wk = (const float*)d_in[2];
  const float* Wv = (const float*)d_in[3];
  const float* Wo = (const float*)d_in[4];
  const float* relb = (const float*)d_in[5];

  const size_t MB8 = (size_t)8 << 20;
  if (ws_size < 6 * MB8 + (1 << 19)) return;

  char* ws = (char*)d_ws;
  f16* Xh = (f16*)(ws + 0 * MB8);
  f16* Wt = (f16*)(ws + 1 * MB8);
  f16* Qh = (f16*)(ws + 2 * MB8);
  f16* Kh = (f16*)(ws + 3 * MB8);
  f16* Vt = (f16*)(ws + 4 * MB8);
  f16* Oh = (f16*)(ws + 5 * MB8);   // doubles as Vrow before attn runs
  f16* brel = (f16*)(ws + 6 * MB8); // [16][4096] f16, log2e-scaled
  f16* Vrow = Oh;                   // dead once transpose_v consumed it

  prep_kernel<<<dim3(32, 32, 6), dim3(32, 8), 0, stream>>>(X, Wq, Wk, Wv, Wo, relb,
                                                           (f16x4*)Xh, Wt, brel);
  gemm_qkv_kernel<<<dim3(24, 32), dim3(256), 0, stream>>>(Xh, Wt, Qh, Kh, Vrow);
  transpose_v_kernel<<<dim3(64, 2, 32), dim3(32, 8), 0, stream>>>(Vrow, Vt);
  attn_kernel<<<dim3(512), dim3(512), 0, stream>>>(Qh, Kh, Vt, brel, Oh);
  gemm_out_kernel<<<dim3(8, 32), dim3(256), 0, stream>>>(Oh, Wt + (size_t)3072 * 1024,
                                                         (float*)d_out);
}